// Round 3
// baseline (380.784 us; speedup 1.0000x reference)
//
#include <hip/hip_runtime.h>

#define NIMG 128
#define NOBJ 32
#define NPRI 8732
#define NCLS 21
#define NP (NIMG * NPRI)
#define SPLIT 4
#define CHUNK (NPRI / SPLIT)   // 2183, exact

static_assert(NP % 256 == 0, "NP must be divisible by 256");
static_assert(NPRI % SPLIT == 0, "chunking must be exact");

// ---------------- helpers ----------------

__device__ __forceinline__ int blockReduceAllInt(int v, int* sred) {
  #pragma unroll
  for (int off = 32; off > 0; off >>= 1) v += __shfl_down(v, off);
  const int tid = threadIdx.x;
  if ((tid & 63) == 0) sred[tid >> 6] = v;
  __syncthreads();
  v = sred[0] + sred[1] + sred[2] + sred[3];
  __syncthreads();
  return v;
}

// ---------------- kernels ----------------

__global__ void k_init(double* acc, int* tp) {
  if (threadIdx.x == 0) { acc[0] = 0.0; acc[1] = 0.0; acc[2] = 0.0; *tp = 0; }
}

// Jaccard over one (image, prior-chunk): per-prior best object + per-object
// partial argmax over the chunk. grid = (SPLIT, NIMG).
__global__ __launch_bounds__(256) void k_overlap(
    const float* __restrict__ boxes, const float* __restrict__ priors,
    float* __restrict__ ovl_buf, unsigned char* __restrict__ obj_buf,
    float* __restrict__ part_v, int* __restrict__ part_p)
{
  const int s = blockIdx.x;
  const int i = blockIdx.y;
  const int tid = threadIdx.x;
  __shared__ float sbx1[NOBJ], sby1[NOBJ], sbx2[NOBJ], sby2[NOBJ], sarea[NOBJ];
  __shared__ float s_cand_v[NOBJ][4];
  __shared__ int   s_cand_p[NOBJ][4];

  if (tid < NOBJ) {
    const float4 b = ((const float4*)boxes)[i * NOBJ + tid];
    sbx1[tid] = b.x; sby1[tid] = b.y; sbx2[tid] = b.z; sby2[tid] = b.w;
    sarea[tid] = (b.z - b.x) * (b.w - b.y);
  }
  __syncthreads();

  // per-object running argmax over this thread's priors (registers, unrolled)
  float obv[NOBJ]; int obp[NOBJ];
  #pragma unroll
  for (int o = 0; o < NOBJ; ++o) { obv[o] = -1.0f; obp[o] = 0x7fffffff; }

  const int base = s * CHUNK;
  for (int p = base + tid; p < base + CHUNK; p += 256) {
    const float4 pr = ((const float4*)priors)[p];
    const float px1 = pr.x - pr.z * 0.5f, py1 = pr.y - pr.w * 0.5f;
    const float px2 = pr.x + pr.z * 0.5f, py2 = pr.y + pr.w * 0.5f;
    const float parea = (px2 - px1) * (py2 - py1);
    float bestv = -1.0f; int besto = 0;
    #pragma unroll
    for (int o = 0; o < NOBJ; ++o) {
      const float ltx = fmaxf(sbx1[o], px1), lty = fmaxf(sby1[o], py1);
      const float rbx = fminf(sbx2[o], px2), rby = fminf(sby2[o], py2);
      const float iw = fmaxf(rbx - ltx, 0.0f), ih = fmaxf(rby - lty, 0.0f);
      const float inter = iw * ih;
      const float ovl = inter / (sarea[o] + parea - inter);
      if (ovl > bestv) { bestv = ovl; besto = o; }       // first-wins (strict >)
      if (ovl > obv[o]) { obv[o] = ovl; obp[o] = p; }    // lowest p wins in-thread
    }
    ovl_buf[i * NPRI + p] = bestv;
    obj_buf[i * NPRI + p] = (unsigned char)besto;
  }

  // cross-lane per-object argmax: butterfly with comparator (v desc, p asc).
  // Lexicographic max is associative+commutative -> order-safe, preserves
  // jnp.argmax lowest-index tie semantics.
  #pragma unroll
  for (int o = 0; o < NOBJ; ++o) {
    float v = obv[o]; int p = obp[o];
    #pragma unroll
    for (int m = 32; m > 0; m >>= 1) {
      const float ov = __shfl_xor(v, m);
      const int   op = __shfl_xor(p, m);
      if (ov > v || (ov == v && op < p)) { v = ov; p = op; }
    }
    if ((tid & 63) == 0) { s_cand_v[o][tid >> 6] = v; s_cand_p[o][tid >> 6] = p; }
  }
  __syncthreads();
  if (tid < NOBJ) {
    float bv = -1.0f; int bp = 0x7fffffff;
    #pragma unroll
    for (int j = 0; j < 4; ++j) {
      const float v = s_cand_v[tid][j]; const int pp = s_cand_p[tid][j];
      if (v > bv || (v == bv && pp < bp)) { bv = v; bp = pp; }
    }
    part_v[(i * SPLIT + s) * NOBJ + tid] = bv;
    part_p[(i * SPLIT + s) * NOBJ + tid] = bp;
  }
}

// Combine partial argmaxes -> prior_for_obj; force-match, threshold, label,
// pack obj|cls, count positives. One block per image.
__global__ __launch_bounds__(256) void k_fin(
    const float* __restrict__ part_v, const int* __restrict__ part_p,
    const int* __restrict__ labels, const float* __restrict__ ovl_buf,
    const unsigned char* __restrict__ obj_buf, int* __restrict__ packed_buf,
    int* __restrict__ n_pos, int* __restrict__ total_pos)
{
  const int i = blockIdx.x;
  const int tid = threadIdx.x;
  __shared__ int s_pfo[NOBJ];
  __shared__ int slab[NOBJ];
  __shared__ int s_red[4];

  if (tid < NOBJ) {
    float bv = -1.0f; int bp = 0x7fffffff;
    #pragma unroll
    for (int s = 0; s < SPLIT; ++s) {
      const float v = part_v[(i * SPLIT + s) * NOBJ + tid];
      const int  pp = part_p[(i * SPLIT + s) * NOBJ + tid];
      if (v > bv || (v == bv && pp < bp)) { bv = v; bp = pp; }
    }
    s_pfo[tid] = bp;
    slab[tid] = labels[i * NOBJ + tid];
  }
  __syncthreads();

  // force-match applied locally (ascending object -> last wins on collision,
  // matching XLA scatter update order), then threshold + label.
  int cnt = 0;
  for (int p = tid; p < NPRI; p += 256) {
    float v = ovl_buf[i * NPRI + p];
    int o = obj_buf[i * NPRI + p];
    #pragma unroll 8
    for (int oo = 0; oo < NOBJ; ++oo) {
      if (s_pfo[oo] == p) { v = 1.0f; o = oo; }
    }
    const int c = (v < 0.5f) ? 0 : slab[o];
    packed_buf[i * NPRI + p] = o | (c << 8);
    cnt += (c != 0) ? 1 : 0;
  }
  cnt = blockReduceAllInt(cnt, s_red);
  if (tid == 0) { n_pos[i] = cnt; atomicAdd(total_pos, cnt); }
}

// CE for every prior + smooth-L1 on positives. One thread per (image,prior).
__global__ __launch_bounds__(256) void k_celoc(
    const float* __restrict__ scores, const float* __restrict__ locs,
    const float* __restrict__ boxes, const float* __restrict__ priors,
    const int* __restrict__ packed_buf, float* __restrict__ negce,
    double* __restrict__ acc)
{
  __shared__ float s_sc[256 * NCLS];
  __shared__ double sredd[8];
  const int tid = threadIdx.x;
  const long base = (long)blockIdx.x * 256;

  // cooperative coalesced stage of this block's 256x21 scores, float4 loads
  const float4* gsc4 = (const float4*)(scores + base * NCLS);  // base*21*4B is 16B-aligned iff base%4==0: base=blk*256 ✓
  float4* s4 = (float4*)s_sc;
  #pragma unroll
  for (int j = tid; j < 256 * NCLS / 4; j += 256) s4[j] = gsc4[j];
  __syncthreads();

  const int idx = (int)base + tid;
  const float* s = &s_sc[tid * NCLS];   // stride 21: 2 lanes/bank, conflict-free
  float mx = s[0];
  #pragma unroll
  for (int c = 1; c < NCLS; ++c) mx = fmaxf(mx, s[c]);
  float se = 0.0f;
  #pragma unroll
  for (int c = 0; c < NCLS; ++c) se += expf(s[c] - mx);
  const float lse = mx + logf(se);

  const int packed = packed_buf[idx];
  const int cls = packed >> 8;
  const float ce = lse - s[cls];
  const bool pos = (cls != 0);
  negce[idx] = pos ? 0.0f : ce;

  float cep = pos ? ce : 0.0f;
  float ls = 0.0f;
  if (pos) {
    const int i = idx / NPRI;
    const int p = idx - i * NPRI;
    const int o = packed & 0xff;
    const float4 b = ((const float4*)boxes)[i * NOBJ + o];
    const float4 pr = ((const float4*)priors)[p];
    const float cx = (b.x + b.z) * 0.5f, cy = (b.y + b.w) * 0.5f;
    const float w = b.z - b.x, h = b.w - b.y;
    const float g0 = (cx - pr.x) / (pr.z / 10.0f);
    const float g1 = (cy - pr.y) / (pr.w / 10.0f);
    const float g2 = logf(w / pr.z) * 5.0f;
    const float g3 = logf(h / pr.w) * 5.0f;
    const float4 pl = ((const float4*)locs)[idx];
    const float d0 = pl.x - g0, d1 = pl.y - g1, d2 = pl.z - g2, d3 = pl.w - g3;
    const float a0 = fabsf(d0), a1 = fabsf(d1), a2 = fabsf(d2), a3 = fabsf(d3);
    ls += (a0 < 1.0f) ? 0.5f * d0 * d0 : a0 - 0.5f;
    ls += (a1 < 1.0f) ? 0.5f * d1 * d1 : a1 - 0.5f;
    ls += (a2 < 1.0f) ? 0.5f * d2 * d2 : a2 - 0.5f;
    ls += (a3 < 1.0f) ? 0.5f * d3 * d3 : a3 - 0.5f;
  }

  #pragma unroll
  for (int off = 32; off > 0; off >>= 1) {
    cep += __shfl_down(cep, off);
    ls  += __shfl_down(ls, off);
  }
  if ((tid & 63) == 0) { sredd[tid >> 6] = (double)cep; sredd[4 + (tid >> 6)] = (double)ls; }
  __syncthreads();
  if (tid == 0) {
    atomicAdd(&acc[0], sredd[0] + sredd[1] + sredd[2] + sredd[3]);
    atomicAdd(&acc[1], sredd[4] + sredd[5] + sredd[6] + sredd[7]);
  }
}

// Per-image sum of top-(3*n_pos) negative CEs via exact radix k-th-largest.
__global__ __launch_bounds__(256) void k_hardneg(
    const float* __restrict__ negce, const int* __restrict__ n_pos,
    double* __restrict__ acc)
{
  __shared__ unsigned s_bits[NPRI];
  __shared__ int s_red[4];
  __shared__ double sredd[4];
  const int i = blockIdx.x;
  const int tid = threadIdx.x;
  // vectorized stage: NPRI = 2183 uint4 exactly; row base i*NPRI*4B is 16B-aligned
  const uint4* g4 = (const uint4*)(negce + i * NPRI);
  uint4* s4 = (uint4*)s_bits;
  for (int j = tid; j < NPRI / 4; j += 256) s4[j] = g4[j];
  __syncthreads();
  const int k = 3 * n_pos[i];
  if (k <= 0) return;  // uniform across block

  unsigned prefix = 0u;
  bool exact = false;
  for (int bit = 30; bit >= 0 && !exact; --bit) {  // nonneg floats: bit-monotone
    const unsigned cand = prefix | (1u << bit);
    int cnt = 0;
    for (int p = tid; p < NPRI; p += 256) cnt += (s_bits[p] >= cand) ? 1 : 0;
    cnt = blockReduceAllInt(cnt, s_red);             // uniform result
    if (cnt >= k) prefix = cand;
    if (cnt == k) exact = true;                      // top-k == {v : v >= cand}
  }

  double sg = 0.0; int cg = 0;
  if (exact) {
    for (int p = tid; p < NPRI; p += 256) {
      const unsigned b = s_bits[p];
      if (b >= prefix) sg += (double)__uint_as_float(b);
    }
  } else {
    // prefix == bits of the k-th largest value v_k (exact)
    for (int p = tid; p < NPRI; p += 256) {
      const unsigned b = s_bits[p];
      if (b > prefix) { sg += (double)__uint_as_float(b); cg++; }
    }
  }
  #pragma unroll
  for (int off = 32; off > 0; off >>= 1) { sg += __shfl_down(sg, off); cg += __shfl_down(cg, off); }
  if ((tid & 63) == 0) { sredd[tid >> 6] = sg; s_red[tid >> 6] = cg; }
  __syncthreads();
  if (tid == 0) {
    const double SG = sredd[0] + sredd[1] + sredd[2] + sredd[3];
    double S;
    if (exact) {
      S = SG;
    } else {
      const int CG = s_red[0] + s_red[1] + s_red[2] + s_red[3];
      S = SG + (double)(k - CG) * (double)__uint_as_float(prefix);
    }
    atomicAdd(&acc[2], S);
  }
}

__global__ void k_final(const double* __restrict__ acc, const int* __restrict__ tp,
                        float* __restrict__ out)
{
  if (threadIdx.x == 0 && blockIdx.x == 0) {
    const double T = (double)(*tp);
    const double conf = (acc[0] + acc[2]) / T;
    const double loc = acc[1] / (T * 4.0);
    out[0] = (float)(conf + loc);
  }
}

// ---------------- launch ----------------

extern "C" void kernel_launch(void* const* d_in, const int* in_sizes, int n_in,
                              void* d_out, int out_size, void* d_ws, size_t ws_size,
                              hipStream_t stream)
{
  const float* locs   = (const float*)d_in[0];  // (N, P, 4)
  const float* scores = (const float*)d_in[1];  // (N, P, 21)
  const float* boxes  = (const float*)d_in[2];  // (N, 32, 4)
  const int*   labels = (const int*)d_in[3];    // (N, 32)
  const float* priors = (const float*)d_in[4];  // (P, 4)
  float* out = (float*)d_out;

  char* ws = (char*)d_ws;
  double* acc       = (double*)ws;                          // 3 doubles
  int*    total_pos = (int*)(ws + 24);
  int*    n_pos     = (int*)(ws + 32);                      // 128 ints
  size_t off = 1024;
  float*  negce  = (float*)(ws + off);  off += (size_t)NP * 4;
  int*    packed = (int*)(ws + off);    off += (size_t)NP * 4;
  float*  ovl    = (float*)(ws + off);  off += (size_t)NP * 4;
  unsigned char* obj = (unsigned char*)(ws + off); off += (size_t)NP;
  off = (off + 255) & ~(size_t)255;
  float*  part_v = (float*)(ws + off);  off += (size_t)NIMG * SPLIT * NOBJ * 4;
  int*    part_p = (int*)(ws + off);    off += (size_t)NIMG * SPLIT * NOBJ * 4;

  hipLaunchKernelGGL(k_init, dim3(1), dim3(64), 0, stream, acc, total_pos);
  hipLaunchKernelGGL(k_overlap, dim3(SPLIT, NIMG), dim3(256), 0, stream,
                     boxes, priors, ovl, obj, part_v, part_p);
  hipLaunchKernelGGL(k_fin, dim3(NIMG), dim3(256), 0, stream,
                     part_v, part_p, labels, ovl, obj, packed, n_pos, total_pos);
  hipLaunchKernelGGL(k_celoc, dim3(NP / 256), dim3(256), 0, stream,
                     scores, locs, boxes, priors, packed, negce, acc);
  hipLaunchKernelGGL(k_hardneg, dim3(NIMG), dim3(256), 0, stream, negce, n_pos, acc);
  hipLaunchKernelGGL(k_final, dim3(1), dim3(1), 0, stream, acc, total_pos, out);
}